// Round 14
// baseline (179.001 us; speedup 1.0000x reference)
//
#include <hip/hip_runtime.h>
#include <stdint.h>

// Problem constants (fixed by the reference)
#define BQ   2
#define NQ   8192
#define D1Q  128
#define D2Q  256
#define OUTQ 128
#define CATQ 384   // D1+D2
#define KQ   16

// ---------------------------------------------------------------------------
// Kernel 1: prep = W transpose + xyz1 norms (tiny).
// ---------------------------------------------------------------------------
__global__ void prep_kernel(const float* __restrict__ W, float* __restrict__ Wt,
                            const float* __restrict__ xyz1,
                            float4* __restrict__ xyz1n) {
    int flat = blockIdx.x * 256 + threadIdx.x;
    if (flat < CATQ * OUTQ) {
        int k = flat >> 7;          // / OUTQ
        int o = flat & (OUTQ - 1);
        Wt[flat] = W[o * CATQ + k];
    }
    if (flat < BQ * NQ) {
        float x = xyz1[flat * 3 + 0];
        float y = xyz1[flat * 3 + 1];
        float z = xyz1[flat * 3 + 2];
        float n;
        {
            #pragma clang fp contract(off)
            float px = x * x, py = y * y, pz = z * z;
            n = (px + py) + pz;
        }
        xyz1n[flat] = make_float4(x, y, z, n);
    }
}

__device__ __forceinline__ void fma4(float4& acc, float a, const float4& w) {
    acc.x = fmaf(a, w.x, acc.x);
    acc.y = fmaf(a, w.y, acc.y);
    acc.z = fmaf(a, w.z, acc.z);
    acc.w = fmaf(a, w.w, acc.w);
}

// numpy-exact squared distance (same rounding as the reference BLAS path)
__device__ __forceinline__ float npy_d2(float4 pt, float qx, float qy, float qz,
                                        float s2) {
    #pragma clang fp contract(off)
    float d0  = pt.x * qx;                 // rounded product
    float dot = fmaf(pt.y, qy, d0);        // explicit FMA chain
    dot       = fmaf(pt.z, qz, dot);
    float tt  = s2 + pt.w;                 // rounded add
    return tt - 2.0f * dot;                // 2*dot exact; rounded sub
}

// 4-op reduced proxy: exact_d2 ~= s2 + red within ~1.5e-5 (values O(30)).
// Phase-1 bound only; never used for keys.
__device__ __forceinline__ float red_r(float4 pt, float qx, float qy, float qz) {
    float dot = fmaf(pt.z, qz, fmaf(pt.y, qy, pt.x * qx));
    return fmaf(-2.0f, dot, pt.w);
}
#define RED_MARGIN 1e-3f   // >= 60x the proxy-vs-exact bound

// full ascending bitonic sort of one uint64 per lane across the wave
__device__ __forceinline__ uint64_t sort64(uint64_t x, int lane) {
    #pragma unroll
    for (int k = 2; k <= 64; k <<= 1) {
        #pragma unroll
        for (int j = k >> 1; j > 0; j >>= 1) {
            uint64_t p = __shfl_xor((unsigned long long)x, j, 64);
            bool keep_min = (((lane & j) == 0) == ((lane & k) == 0));
            bool pless    = p < x;
            x = (pless == keep_min) ? p : x;   // ties: same value either way
        }
    }
    return x;
}

// ---------------------------------------------------------------------------
// Kernel 2 (R14): fused NN + interp + GEMM. Per block: 16 queries.
// Change vs R13 (counters: DS ~66us co-bound with VALU ~67us; stage-3 GEMM
// = 576 b128/wave, with W-reads duplicated across lane halves):
//  Stage 3 k-split: khalf=(tid>>5)&1 -> lanes 0-31 take k g*8..+3, lanes
//  32-63 take g*8+4..+7. Thread = 4 rows x 4 cols x half-k. Each W b128 now
//  serves 8 k/wave (1KB distinct), each A b128 serves 4 rows (2-addr
//  broadcast): 576 -> 384 b128/wave. One-time acc += shfl_xor(acc,32)
//  reduction merges the k-halves (reassociation ~1e-6, slack 5e-2).
// NN stages unchanged from R13 (selection bit-identical).
// ---------------------------------------------------------------------------
__global__ __launch_bounds__(256, 4) void fused_kernel(
        const float4* __restrict__ xyz1n, const float* __restrict__ xyz2,
        const float* __restrict__ points1, const float* __restrict__ points2,
        const float* __restrict__ Wt, const float* __restrict__ bias,
        float* __restrict__ out) {
    __shared__ __align__(16) char smem[40960];
    float4*   xyzt4 = (float4*)smem;                 // [0,16K)  stage 1
    uint64_t* wball = (uint64_t*)(smem + 16384);     // [16K,32K) stage 1: [16][128]
    float*    cat   = (float*)smem;                  // [0,24K)  stages 2-3
    float*    Wl    = (float*)(smem + 24576);        // [24K,40K) stage 3

    const int tid   = threadIdx.x;
    const int lane  = tid & 63;
    const int w     = tid >> 6;
    const int qbase = blockIdx.x * 16 + w * 4;     // wave's 4 queries
    const int b     = (blockIdx.x * 16) >> 13;     // uniform per block

    float qx[4], qy[4], qz[4], s2[4];
    #pragma unroll
    for (int j = 0; j < 4; ++j) {
        const float* qp = xyz2 + (size_t)(qbase + j) * 3;
        qx[j] = qp[0]; qy[j] = qp[1]; qz[j] = qp[2];
        {
            #pragma clang fp contract(off)
            float px = qx[j] * qx[j], py = qy[j] * qy[j], pz = qz[j] * qz[j];
            s2[j] = (px + py) + pz;
        }
    }

    const float4* xb = xyz1n + (size_t)b * NQ;

    // ------- Phase 1: reduced-proxy lane-min scan over HALF the points -------
    float mn[4];
    #pragma unroll
    for (int j = 0; j < 4; ++j) mn[j] = __uint_as_float(0x7F800000u);

    for (int tile = 0; tile < 4; ++tile) {
        __syncthreads();
        {
            const float4* s4 = xb + tile * 1024;
            #pragma unroll
            for (int v = tid; v < 1024; v += 256) xyzt4[v] = s4[v];
        }
        __syncthreads();
        #pragma unroll 4
        for (int s = 0; s < 16; ++s) {
            float4 pt = xyzt4[s * 64 + lane];
            #pragma unroll
            for (int j = 0; j < 4; ++j)
                mn[j] = fminf(mn[j], red_r(pt, qx[j], qy[j], qz[j]));
        }
    }

    // 4 float bitonic sorts of lane minima; that[j] = s2 + rank15 + margin
    float that[4];
    #pragma unroll
    for (int j = 0; j < 4; ++j) {
        float x = mn[j];
        #pragma unroll
        for (int k = 2; k <= 64; k <<= 1) {
            #pragma unroll
            for (int jj = k >> 1; jj > 0; jj >>= 1) {
                float px = __shfl_xor(x, jj, 64);
                bool keep_min = (((lane & jj) == 0) == ((lane & k) == 0));
                float mnv = fminf(x, px), mxv = fmaxf(x, px);
                x = keep_min ? mnv : mxv;
            }
        }
        that[j] = s2[j] + __shfl(x, 15, 64) + RED_MARGIN;
    }

    // ------- Phase 2 (exact, branchless d2): gated compaction -------
    uint32_t cnt[4] = {0u, 0u, 0u, 0u};
    for (int tt = 0; tt < 8; ++tt) {
        const int tile = (3 + tt) & 7;             // tile 3 still resident
        if (tt > 0) {
            __syncthreads();
            const float4* s4 = xb + tile * 1024;
            #pragma unroll
            for (int v = tid; v < 1024; v += 256) xyzt4[v] = s4[v];
            __syncthreads();
        }
        const uint32_t base = (uint32_t)tile * 1024u;
        #pragma unroll 4
        for (int s = 0; s < 16; ++s) {
            float4 pt = xyzt4[s * 64 + lane];
            const uint32_t pidx = base + (uint32_t)(s * 64 + lane);
            #pragma unroll
            for (int j = 0; j < 4; ++j) {
                float d2 = npy_d2(pt, qx[j], qy[j], qz[j], s2[j]);
                bool  v  = (d2 <= that[j]);
                uint64_t mask = __ballot((int)v);
                if (mask != 0ull) {                // scalar gate
                    if (v) {
                        uint32_t below = __builtin_amdgcn_mbcnt_hi(
                            (uint32_t)(mask >> 32),
                            __builtin_amdgcn_mbcnt_lo((uint32_t)mask, 0u));
                        uint32_t pos    = cnt[j] + below;
                        uint32_t bits   = __float_as_uint(d2);
                        uint32_t mapped = bits ^ (0x80000000u |
                                          (uint32_t)((int32_t)bits >> 31));
                        if (pos < 128u)
                            wball[(w * 4 + j) * 128 + pos] =
                                ((uint64_t)mapped << 32) | (uint64_t)pidx;
                    }
                    cnt[j] += (uint32_t)__popcll(mask);
                }
            }
        }
    }

    // ---------------- per-query selection + weights ----------------
    int   myidxA[4];
    float mywgtA[4];
    #pragma unroll
    for (int j = 0; j < 4; ++j) {
        const uint64_t* wb = wball + (size_t)(w * 4 + j) * 128;
        const uint32_t c = cnt[j];
        uint64_t mykey;
        if (c <= 64u) {                            // normal path
            uint64_t k0 = (lane < (int)c) ? wb[lane] : ~0ull;
            mykey = sort64(k0, lane);
        } else {                                   // uniform fallback
            uint32_t cc = c > 128u ? 128u : c;
            uint64_t k0 = wb[lane];
            uint64_t k1 = (lane + 64 < (int)cc) ? wb[lane + 64] : ~0ull;
            k0 = sort64(k0, lane);
            k1 = sort64(k1, lane);
            uint64_t t1 = __shfl((unsigned long long)k1, lane & 15, 64);
            uint64_t km = (lane < 16) ? k0 : ((lane < 32) ? t1 : ~0ull);
            mykey = sort64(km, lane);
        }
        uint32_t mhi   = (uint32_t)(mykey >> 32);
        uint32_t rbits = (mhi & 0x80000000u) ? (mhi ^ 0x80000000u) : ~mhi;
        float    d2w   = __uint_as_float(rbits);
        myidxA[j] = (int)(uint32_t)(mykey & 0xFFFFFFFFull);
        float recip = (lane < KQ) ? (1.0f / (d2w + 1e-8f)) : 0.0f;
        float tot = recip;
        #pragma unroll
        for (int sh = 1; sh < 16; sh <<= 1) tot += __shfl_xor(tot, sh, 64);
        mywgtA[j] = recip / tot;                   // valid in lanes 0..15
    }

    // LDS reuse boundary: all waves done with xyzt4 + wbuf
    __syncthreads();

    // ---------------- Stage 2: build cat[16][384] in LDS ----------------
    const float* p2b = points2 + (size_t)b * NQ * D2Q;
    #pragma unroll
    for (int j = 0; j < 4; ++j) {
        const int qi = w * 4 + j;
        // p1 part: 128 floats, lanes 0..31
        if (lane < 32) {
            float4 p = ((const float4*)(points1 + (size_t)(qbase + j) * D1Q))[lane];
            *(float4*)&cat[qi * CATQ + lane * 4] = p;
        }
        // interp part: 256 floats, all 64 lanes; k ascending (reference order)
        float4 acc = make_float4(0.f, 0.f, 0.f, 0.f);
        #pragma unroll
        for (int k = 0; k < KQ; ++k) {
            int   kk = __builtin_amdgcn_readlane(myidxA[j], k);
            float wk = __uint_as_float((uint32_t)__builtin_amdgcn_readlane(
                           (int)__float_as_uint(mywgtA[j]), k));
            float4 row = ((const float4*)(p2b + (size_t)kk * D2Q))[lane];
            acc.x = fmaf(wk, row.x, acc.x);
            acc.y = fmaf(wk, row.y, acc.y);
            acc.z = fmaf(wk, row.z, acc.z);
            acc.w = fmaf(wk, row.w, acc.w);
        }
        *(float4*)&cat[qi * CATQ + D1Q + lane * 4] = acc;
    }
    __syncthreads();

    // ------- Stage 3: k-split block GEMM cat @ Wt + bias -------
    // thread = 4 rows x 4 cols x half-k; rg = wave id (rows rg*4..+3),
    // khalf = intra-wave half, o0 = col base.
    const int o0    = (tid & 31) * 4;
    const int khalf = (tid >> 5) & 1;
    const int rg    = tid >> 6;

    float4 acc[4];
    #pragma unroll
    for (int r = 0; r < 4; ++r) acc[r] = make_float4(0.f, 0.f, 0.f, 0.f);

    for (int c = 0; c < 12; ++c) {
        if (c) __syncthreads();           // protect previous chunk's readers
        {
            const float4* src = (const float4*)(Wt + (size_t)c * 32 * OUTQ);
            #pragma unroll
            for (int i = 0; i < 4; ++i)
                ((float4*)Wl)[tid + 256 * i] = src[tid + 256 * i];
        }
        __syncthreads();

        const int kb = c * 32;
        #pragma unroll
        for (int g = 0; g < 4; ++g) {
            const int kk = g * 8 + khalf * 4;     // this half's 4 k-values
            const float* wb = Wl + kk * OUTQ + o0;
            float4 w0 = *(const float4*)(wb + 0 * OUTQ);
            float4 w1 = *(const float4*)(wb + 1 * OUTQ);
            float4 w2 = *(const float4*)(wb + 2 * OUTQ);
            float4 w3 = *(const float4*)(wb + 3 * OUTQ);
            #pragma unroll
            for (int r = 0; r < 4; ++r) {
                float4 a = *(const float4*)&cat[(rg * 4 + r) * CATQ + kb + kk];
                fma4(acc[r], a.x, w0); fma4(acc[r], a.y, w1);
                fma4(acc[r], a.z, w2); fma4(acc[r], a.w, w3);
            }
        }
    }

    // merge k-halves: partner lane is lane^32
    #pragma unroll
    for (int r = 0; r < 4; ++r) {
        acc[r].x += __shfl_xor(acc[r].x, 32, 64);
        acc[r].y += __shfl_xor(acc[r].y, 32, 64);
        acc[r].z += __shfl_xor(acc[r].z, 32, 64);
        acc[r].w += __shfl_xor(acc[r].w, 32, 64);
    }

    if (khalf == 0) {
        float4 bv = *(const float4*)(bias + o0);
        const int q0 = blockIdx.x * 16 + rg * 4;
        #pragma unroll
        for (int r = 0; r < 4; ++r) {
            float4 rr = acc[r];
            rr.x += bv.x; rr.y += bv.y; rr.z += bv.z; rr.w += bv.w;
            *(float4*)&out[(size_t)(q0 + r) * OUTQ + o0] = rr;
        }
    }
}

// ---------------------------------------------------------------------------
// Launch
// ---------------------------------------------------------------------------
extern "C" void kernel_launch(void* const* d_in, const int* in_sizes, int n_in,
                              void* d_out, int out_size, void* d_ws, size_t ws_size,
                              hipStream_t stream) {
    const float* xyz1    = (const float*)d_in[0];
    const float* xyz2    = (const float*)d_in[1];
    const float* points1 = (const float*)d_in[2];
    const float* points2 = (const float*)d_in[3];
    const float* W       = (const float*)d_in[4];
    const float* bias    = (const float*)d_in[5];

    float* wsf  = (float*)d_ws;
    float* Wt   = wsf;                         // 384*128 = 49152 floats
    float4* xyz1n = (float4*)(wsf + 49152);    // 16384 float4

    prep_kernel<<<192, 256, 0, stream>>>(W, Wt, xyz1, xyz1n);
    fused_kernel<<<(BQ * NQ) / 16, 256, 0, stream>>>(
        xyz1n, xyz2, points1, points2, Wt, bias, (float*)d_out);
}